// Round 5
// baseline (3791.227 us; speedup 1.0000x reference)
//
#include <hip/hip_runtime.h>
#include <stdint.h>

#define B_ 32
#define T_ 512
#define E_ 1024
#define H_ 1024
#define NWAVE 64   // k_rnn: 64 blocks x 1 wave; wave j owns h-cols [16j,16j+16)

typedef __attribute__((ext_vector_type(8))) short short8;
typedef __attribute__((ext_vector_type(4))) float floatx4;
typedef __attribute__((ext_vector_type(4))) int int4v;
typedef unsigned long long ull;

union U16 { ull u[2]; short8 s; int4v v; };

__device__ __forceinline__ unsigned short bf16_of(float f) {
    unsigned u = __float_as_uint(f);
    return (unsigned short)((u + 0x8000u) >> 16);   // round-half-up to bf16
}

__device__ __forceinline__ short8 load_bf8(const float* __restrict__ p) {
    const float4* q = (const float4*)p;
    float4 v0 = q[0];
    float4 v1 = q[1];
    short8 r;
    r[0] = (short)bf16_of(v0.x); r[1] = (short)bf16_of(v0.y);
    r[2] = (short)bf16_of(v0.z); r[3] = (short)bf16_of(v0.w);
    r[4] = (short)bf16_of(v1.x); r[5] = (short)bf16_of(v1.y);
    r[6] = (short)bf16_of(v1.z); r[7] = (short)bf16_of(v1.w);
    return r;
}

// ---------------------------------------------------------------------------
// K1: xp[n,h] = sum_e x[n,e] * Wih[h,e] + (bih[h]+bhh[h])  (unchanged)
// ---------------------------------------------------------------------------
__global__ __launch_bounds__(256) void k_xp(const float* __restrict__ x,
                                            const float* __restrict__ Wih,
                                            const float* __restrict__ bih,
                                            const float* __restrict__ bhh,
                                            float* __restrict__ out) {
    const int tid  = threadIdx.x;
    const int w    = tid >> 6;
    const int lane = tid & 63;
    const int l15  = lane & 15;
    const int quad = lane >> 4;
    const int rb = blockIdx.x & 127;
    const int cb = blockIdx.x >> 7;
    const int row_base = rb * 128 + w * 32;
    const int col_base = cb * 128;

    floatx4 acc[2][8];
#pragma unroll
    for (int i = 0; i < 2; i++)
#pragma unroll
        for (int j = 0; j < 8; j++) acc[i][j] = (floatx4)0.0f;

    for (int k0 = 0; k0 < E_; k0 += 32) {
        const int koff = k0 + quad * 8;
        short8 a[2];
#pragma unroll
        for (int mt = 0; mt < 2; mt++)
            a[mt] = load_bf8(x + (size_t)(row_base + mt * 16 + l15) * E_ + koff);
        short8 b[8];
#pragma unroll
        for (int nt = 0; nt < 8; nt++)
            b[nt] = load_bf8(Wih + (size_t)(col_base + nt * 16 + l15) * E_ + koff);
#pragma unroll
        for (int mt = 0; mt < 2; mt++)
#pragma unroll
            for (int nt = 0; nt < 8; nt++)
                acc[mt][nt] = __builtin_amdgcn_mfma_f32_16x16x32_bf16(
                    a[mt], b[nt], acc[mt][nt], 0, 0, 0);
    }

#pragma unroll
    for (int nt = 0; nt < 8; nt++) {
        const int col = col_base + nt * 16 + l15;
        const float bias = bih[col] + bhh[col];
#pragma unroll
        for (int mt = 0; mt < 2; mt++) {
            const int row = row_base + mt * 16 + quad * 4;
#pragma unroll
            for (int r = 0; r < 4; r++)
                out[(size_t)(row + r) * H_ + col] = acc[mt][nt][r] + bias;
        }
    }
}

// ---------------------------------------------------------------------------
// ws layout (u32 units): [0,1024) flags (64 x 64B-stride); ring slots at
// 1024 + s*16384, each 64KB blocked bf16 (lo 32KB / hi 32KB halves).
// Slot ring-1 holds h_{-1} = 0.
// ---------------------------------------------------------------------------
__global__ void k_init(unsigned* __restrict__ ws, int ring) {
    const int i = blockIdx.x * blockDim.x + threadIdx.x;   // 0..16383
    if (i < 1024) ws[i] = 0u;
    ws[1024 + (ring - 1) * 16384 + i] = 0u;
}

// ---------------------------------------------------------------------------
// K3 v5: wave-dataflow recurrence with RELEASE/ACQUIRE fence protocol.
//
// Round-4 evidence: agent-scope write-through h stores ack at HBM (~2000cyc
// drain; WRITE_SIZE showed h at HBM) and flag polls fetch from HBM (FETCH
// +148MB) -> the 4-hop sync chain runs at DRAM latency. Fix: keep all data
// in the cache hierarchy.
//   Producer: NORMAL cached h stores (L2 ack ~300cyc) ->
//             fence(release, agent) = s_waitcnt + buffer_wbl2 (flush tiny
//             per-step dirty set to LLC) -> atomic flag store.
//   Consumer: lane-parallel flag poll -> fence(acquire, agent) = buffer_inv
//             (every step) -> normal cached loads, served by the LLC.
// out stores / xp loads are NONTEMPORAL: no L2 allocation -> they neither
// enlarge the wbl2 dirty set nor trigger RFO; their HBM latency sits a full
// step off the critical path.
// Skew safety: flag-gated skew <= 1 step; ring>=2 suffices (ring=4 used).
// ---------------------------------------------------------------------------
__global__ __launch_bounds__(64, 1) void k_rnn(const float* __restrict__ Whh,
                                               float* __restrict__ out,
                                               unsigned* __restrict__ ws,
                                               int ring) {
    const int lane = threadIdx.x;     // 0..63
    const int l15  = lane & 15;
    const int quad = lane >> 4;
    const int wid  = blockIdx.x;      // 0..63
    const int j0   = wid * 16;

    unsigned* flags = ws;             // 64 flags, 64B stride

    // Producer store slot (16B units) and LDS transpose read offset (bytes).
    const int mt_s = lane >> 5;
    const int sub  = (lane >> 4) & 1;
    const int m_s  = lane & 15;
    const int slot = (wid >> 1) * 128 + mt_s * 64 + (wid & 1) * 32 + sub * 16 + m_s;
    const int lds_off = mt_s * 512 + m_s * 32 + sub * 16;

    __shared__ unsigned short sh[512];   // [batch 0..31][col 0..15]

    // Full-K W_hh B-fragments: wreg[c] covers k in [32c + quad*8, +8), col j0+l15.
    short8 wreg[32];
#pragma unroll
    for (int c = 0; c < 32; c++)
        wreg[c] = load_bf8(Whh + (size_t)(j0 + l15) * H_ + c * 32 + quad * 8);

#pragma unroll 1
    for (int t = 0; t < T_; t++) {
        const int rs  = (t + ring - 1) & (ring - 1);   // read slot (h_{t-1})
        const int wsl = t & (ring - 1);                // write slot (h_t)
        const ull* hA = (const ull*)(ws + 1024 + rs * 16384);
        const ull* hB = hA + 4096;
        ull* nxA = (ull*)(ws + 1024 + wsl * 16384);
        ull* nxB = nxA + 4096;

        // xp prefetch (independent of h), nontemporal: no L2 allocation.
        float xv[2][4];
#pragma unroll
        for (int mt = 0; mt < 2; mt++)
#pragma unroll
            for (int r = 0; r < 4; r++) {
                const int b = mt * 16 + quad * 4 + r;
                xv[mt][r] = __builtin_nontemporal_load(
                    out + ((size_t)b * T_ + t) * H_ + j0 + l15);
            }

        if (t > 0) {
            const unsigned tv = (unsigned)t;
            while (true) {
                unsigned v = __hip_atomic_load(&flags[lane * 16], __ATOMIC_RELAXED,
                                               __HIP_MEMORY_SCOPE_AGENT);
                if (__ballot(v < tv) == 0ull) break;
            }
            // acquire: invalidate stale L1/L2 so loads below see LLC data.
            __builtin_amdgcn_fence(__ATOMIC_ACQUIRE, "agent");
        }

        floatx4 acc[2];
        acc[0] = (floatx4)0.0f;
        acc[1] = (floatx4)0.0f;
#pragma unroll
        for (int c = 0; c < 32; c++) {
#pragma unroll
            for (int mt = 0; mt < 2; mt++) {
                U16 u;
                u.u[0] = hA[(c * 2 + mt) * 64 + lane];   // cached, LLC-served
                u.u[1] = hB[(c * 2 + mt) * 64 + lane];
                acc[mt] = __builtin_amdgcn_mfma_f32_16x16x32_bf16(u.s, wreg[c],
                                                                  acc[mt], 0, 0, 0);
            }
        }

        // tanh in-register (D layout: col=l15, batch=mt*16+quad*4+r),
        // bf16 -> LDS transpose to A-layout (DS ops in-order per wave).
        float hv[2][4];
#pragma unroll
        for (int mt = 0; mt < 2; mt++)
#pragma unroll
            for (int r = 0; r < 4; r++) {
                const float p = xv[mt][r] + acc[mt][r];
                const float h = 1.0f - 2.0f / (__expf(2.0f * p) + 1.0f);
                hv[mt][r] = h;
                sh[(mt * 16 + quad * 4 + r) * 16 + l15] = bf16_of(h);
            }

        // One 16B A-layout chunk per lane -> 2 coalesced NORMAL u64 stores
        // (land dirty in local L2; flushed to LLC by the release fence).
        U16 pk;
        pk.v = *(const int4v*)((const char*)sh + lds_off);
        nxA[slot] = pk.u[0];
        nxB[slot] = pk.u[1];

        // release: s_waitcnt (cheap L2 acks) + buffer_wbl2 (dirty set -> LLC)
        __builtin_amdgcn_fence(__ATOMIC_RELEASE, "agent");
        if (lane == 0)
            __hip_atomic_store(&flags[wid * 16], (unsigned)(t + 1),
                               __ATOMIC_RELAXED, __HIP_MEMORY_SCOPE_AGENT);

        // fp32 outputs: nontemporal, fire-and-forget, off the critical path.
#pragma unroll
        for (int mt = 0; mt < 2; mt++)
#pragma unroll
            for (int r = 0; r < 4; r++) {
                const int b = mt * 16 + quad * 4 + r;
                __builtin_nontemporal_store(
                    hv[mt][r], out + ((size_t)b * T_ + t) * H_ + j0 + l15);
            }
    }
}

// ---------------------------------------------------------------------------
extern "C" void kernel_launch(void* const* d_in, const int* in_sizes, int n_in,
                              void* d_out, int out_size, void* d_ws, size_t ws_size,
                              hipStream_t stream) {
    const float* x   = (const float*)d_in[0];
    const float* Wih = (const float*)d_in[1];
    const float* Whh = (const float*)d_in[2];
    const float* bih = (const float*)d_in[3];
    const float* bhh = (const float*)d_in[4];
    float* out = (float*)d_out;
    unsigned* ws = (unsigned*)d_ws;

    // ring=4 needs 4KB flags + 4*64KB = 260KB+; fallback ring=2 fits 132KB.
    const size_t need4 = (size_t)(1024 + 4 * 16384) * sizeof(unsigned);
    const int ring = (ws_size >= need4) ? 4 : 2;

    k_init<<<64, 256, 0, stream>>>(ws, ring);
    k_xp<<<128 * 8, 256, 0, stream>>>(x, Wih, bih, bhh, out);
    k_rnn<<<NWAVE, 64, 0, stream>>>(Whh, out, ws, ring);
}

// Round 6
// 2587.702 us; speedup vs baseline: 1.4651x; 1.4651x over previous
//
#include <hip/hip_runtime.h>
#include <stdint.h>

#define B_ 32
#define T_ 512
#define E_ 1024
#define H_ 1024
#define NWAVE 64   // k_rnn: 64 blocks; wave j owns h-cols [16j,16j+16)

typedef __attribute__((ext_vector_type(8))) short short8;
typedef __attribute__((ext_vector_type(4))) float floatx4;
typedef __attribute__((ext_vector_type(4))) int int4v;
typedef unsigned long long ull;

union U16 { ull u[2]; short8 s; int4v v; };

__device__ __forceinline__ unsigned short bf16_of(float f) {
    unsigned u = __float_as_uint(f);
    return (unsigned short)((u + 0x8000u) >> 16);   // round-half-up to bf16
}

__device__ __forceinline__ short8 load_bf8(const float* __restrict__ p) {
    const float4* q = (const float4*)p;
    float4 v0 = q[0];
    float4 v1 = q[1];
    short8 r;
    r[0] = (short)bf16_of(v0.x); r[1] = (short)bf16_of(v0.y);
    r[2] = (short)bf16_of(v0.z); r[3] = (short)bf16_of(v0.w);
    r[4] = (short)bf16_of(v1.x); r[5] = (short)bf16_of(v1.y);
    r[6] = (short)bf16_of(v1.z); r[7] = (short)bf16_of(v1.w);
    return r;
}

// ---------------------------------------------------------------------------
// K1: xp[n,h] = sum_e x[n,e] * Wih[h,e] + (bih[h]+bhh[h])
// Round-6 change: block swizzle rb=bid>>3, cb=bid&7 so the 8 blocks sharing
// an x row-block are temporally adjacent -> x fetched ~once from HBM.
// ---------------------------------------------------------------------------
__global__ __launch_bounds__(256) void k_xp(const float* __restrict__ x,
                                            const float* __restrict__ Wih,
                                            const float* __restrict__ bih,
                                            const float* __restrict__ bhh,
                                            float* __restrict__ out) {
    const int tid  = threadIdx.x;
    const int w    = tid >> 6;
    const int lane = tid & 63;
    const int l15  = lane & 15;
    const int quad = lane >> 4;
    const int rb = blockIdx.x >> 3;      // 128 row-blocks of 128 rows
    const int cb = blockIdx.x & 7;       // 8 col-blocks of 128 cols
    const int row_base = rb * 128 + w * 32;
    const int col_base = cb * 128;

    floatx4 acc[2][8];
#pragma unroll
    for (int i = 0; i < 2; i++)
#pragma unroll
        for (int j = 0; j < 8; j++) acc[i][j] = (floatx4)0.0f;

    for (int k0 = 0; k0 < E_; k0 += 32) {
        const int koff = k0 + quad * 8;
        short8 a[2];
#pragma unroll
        for (int mt = 0; mt < 2; mt++)
            a[mt] = load_bf8(x + (size_t)(row_base + mt * 16 + l15) * E_ + koff);
        short8 b[8];
#pragma unroll
        for (int nt = 0; nt < 8; nt++)
            b[nt] = load_bf8(Wih + (size_t)(col_base + nt * 16 + l15) * E_ + koff);
#pragma unroll
        for (int mt = 0; mt < 2; mt++)
#pragma unroll
            for (int nt = 0; nt < 8; nt++)
                acc[mt][nt] = __builtin_amdgcn_mfma_f32_16x16x32_bf16(
                    a[mt], b[nt], acc[mt][nt], 0, 0, 0);
    }

#pragma unroll
    for (int nt = 0; nt < 8; nt++) {
        const int col = col_base + nt * 16 + l15;
        const float bias = bih[col] + bhh[col];
#pragma unroll
        for (int mt = 0; mt < 2; mt++) {
            const int row = row_base + mt * 16 + quad * 4;
#pragma unroll
            for (int r = 0; r < 4; r++)
                out[(size_t)(row + r) * H_ + col] = acc[mt][nt][r] + bias;
        }
    }
}

// ---------------------------------------------------------------------------
// ws layout (u32 units): [0,1024) flags (64 x 64B-stride); ring slots at
// 1024 + s*16384, each 64KB blocked bf16 (lo 32KB / hi 32KB). Slot ring-1
// holds h_{-1} = 0.
// ---------------------------------------------------------------------------
__global__ void k_init(unsigned* __restrict__ ws, int ring) {
    const int i = blockIdx.x * blockDim.x + threadIdx.x;   // 0..16383
    if (i < 1024) ws[i] = 0u;
    ws[1024 + (ring - 1) * 16384 + i] = 0u;
}

// ---------------------------------------------------------------------------
// K3 v6: wave-role split. 64 blocks x 128 threads (2 waves).
//
// Wave 0 (sync/compute): R4's protocol verbatim — poll 64 flags (agent
// atomics), acquire fence every `ring` steps, blocked h loads, 64 MFMAs,
// tanh, LDS transpose, 2 coalesced write-through u64 h stores, vmcnt(0),
// flag. Crucially its VMEM stream contains NOTHING else: the per-poll
// vmcnt(0) (compiler-inserted, oldest-first semantics) no longer drains
// fp32-out HBM write-acks or xp HBM loads — R2..R5's hidden serial cost.
//
// Wave 1 (service): loads xp(t+1) from HBM -> sh_xp[(t+1)&1]; reads h_t
// fp32 from sh_hf[t&1] after the step barrier; writes out(t-1) from regs.
// All its HBM latency is one step off the critical path.
//
// Handoff: one s_barrier per step (both waves execute 1 prologue + T
// barriers). Parity double-buffers make all LDS cross-wave accesses
// race-free (see inline notes).
// ---------------------------------------------------------------------------
__global__ __launch_bounds__(128, 1) void k_rnn(const float* __restrict__ Whh,
                                                float* __restrict__ out,
                                                unsigned* __restrict__ ws,
                                                int ring) {
    const int tid  = threadIdx.x;
    const int wv   = tid >> 6;        // 0 = sync/compute, 1 = service
    const int lane = tid & 63;
    const int wid  = blockIdx.x;      // 0..63
    const int j0   = wid * 16;

    unsigned* flags = ws;             // 64 flags, 64B stride

    __shared__ unsigned short sh_h[512];   // A-layout transpose (wave0 private)
    __shared__ float sh_hf[2][512];        // h fp32 handoff w0->w1 [parity][b*16+col]
    __shared__ float sh_xp[2][512];        // xp staging w1->w0 [parity][b*16+col]

    if (wv == 0) {
        const int l15  = lane & 15;
        const int quad = lane >> 4;
        const int mt_s = lane >> 5;
        const int sub  = (lane >> 4) & 1;
        const int m_s  = lane & 15;
        const int slot = (wid >> 1) * 128 + mt_s * 64 + (wid & 1) * 32 + sub * 16 + m_s;
        const int lds_off = mt_s * 512 + m_s * 32 + sub * 16;   // bytes into sh_h

        // Full-K W_hh B-fragments (128 VGPRs).
        short8 wreg[32];
#pragma unroll
        for (int c = 0; c < 32; c++)
            wreg[c] = load_bf8(Whh + (size_t)(j0 + l15) * H_ + c * 32 + quad * 8);

        __syncthreads();   // prologue: wave1 filled sh_xp[0]

#pragma unroll 1
        for (int t = 0; t < T_; t++) {
            const int rs  = (t + ring - 1) & (ring - 1);
            const int wsl = t & (ring - 1);
            const ull* hA = (const ull*)(ws + 1024 + rs * 16384);
            const ull* hB = hA + 4096;
            ull* nxA = (ull*)(ws + 1024 + wsl * 16384);
            ull* nxB = nxA + 4096;

            if (t > 0) {
                const unsigned tv = (unsigned)t;
                while (true) {
                    unsigned v = __hip_atomic_load(&flags[lane * 16],
                                                   __ATOMIC_RELAXED,
                                                   __HIP_MEMORY_SCOPE_AGENT);
                    if (__ballot(v < tv) == 0ull) break;
                }
                if ((t & (ring - 1)) == 0)
                    __builtin_amdgcn_fence(__ATOMIC_ACQUIRE, "agent");
                else
                    asm volatile("" ::: "memory");
            }

            floatx4 acc[2];
            acc[0] = (floatx4)0.0f;
            acc[1] = (floatx4)0.0f;
#pragma unroll
            for (int c = 0; c < 32; c++) {
#pragma unroll
                for (int mt = 0; mt < 2; mt++) {
                    U16 u;
                    u.u[0] = hA[(c * 2 + mt) * 64 + lane];
                    u.u[1] = hB[(c * 2 + mt) * 64 + lane];
                    acc[mt] = __builtin_amdgcn_mfma_f32_16x16x32_bf16(
                        u.s, wreg[c], acc[mt], 0, 0, 0);
                }
            }

            // xp from LDS (staged by wave1 at iteration t-1), tanh, handoffs.
#pragma unroll
            for (int mt = 0; mt < 2; mt++)
#pragma unroll
                for (int r = 0; r < 4; r++) {
                    const int b = mt * 16 + quad * 4 + r;
                    const float p = sh_xp[t & 1][b * 16 + l15] + acc[mt][r];
                    const float h = 1.0f - 2.0f / (__expf(2.0f * p) + 1.0f);
                    sh_hf[t & 1][b * 16 + l15] = h;          // -> wave1 (out)
                    sh_h[b * 16 + l15] = bf16_of(h);         // -> transpose
                }

            // In-wave DS ordering: reads below see the writes above.
            U16 pk;
            pk.v = *(const int4v*)((const char*)sh_h + lds_off);
            __hip_atomic_store(nxA + slot, pk.u[0], __ATOMIC_RELAXED,
                               __HIP_MEMORY_SCOPE_AGENT);
            __hip_atomic_store(nxB + slot, pk.u[1], __ATOMIC_RELAXED,
                               __HIP_MEMORY_SCOPE_AGENT);

            asm volatile("s_waitcnt vmcnt(0)" ::: "memory");  // 2 MALL acks only
            if (lane == 0)
                __hip_atomic_store(&flags[wid * 16], (unsigned)(t + 1),
                                   __ATOMIC_RELAXED, __HIP_MEMORY_SCOPE_AGENT);

            __syncthreads();   // step barrier (wave1 handoff)
        }
    } else {
        // ---- service wave: xp prefetch + fp32 out writeback ----
        const int b  = lane >> 1;           // batch 0..31
        const int cs = (lane & 1) * 8;      // col offset 0 or 8
        const float* xp_base = out + (size_t)b * T_ * H_ + j0 + cs;
        float*       out_base = out + (size_t)b * T_ * H_ + j0 + cs;

        // prologue: stage xp(0) -> sh_xp[0]
        {
            float4 v0 = *(const float4*)(xp_base + 0);
            float4 v1 = *(const float4*)(xp_base + 4);
            *(float4*)&sh_xp[0][b * 16 + cs]     = v0;
            *(float4*)&sh_xp[0][b * 16 + cs + 4] = v1;
        }
        __syncthreads();

        float hold[8];
#pragma unroll 1
        for (int t = 0; t < T_; t++) {
            // xp loads for t+1 first (so the ds_write wait targets them).
            float4 v0, v1;
            const bool more = (t + 1 < T_);
            if (more) {
                v0 = *(const float4*)(xp_base + (size_t)(t + 1) * H_);
                v1 = *(const float4*)(xp_base + (size_t)(t + 1) * H_ + 4);
            }
            // out stores for step t-1 (fire-and-forget; acks stall wave1 only)
            if (t > 0) {
#pragma unroll
                for (int k = 0; k < 8; k++)
                    __builtin_nontemporal_store(
                        hold[k], out_base + (size_t)(t - 1) * H_ + k);
            }
            if (more) {
                *(float4*)&sh_xp[(t + 1) & 1][b * 16 + cs]     = v0;
                *(float4*)&sh_xp[(t + 1) & 1][b * 16 + cs + 4] = v1;
            }
            __syncthreads();   // step barrier: wave0's sh_hf[t&1] now valid
#pragma unroll
            for (int k = 0; k < 8; k++)
                hold[k] = sh_hf[t & 1][b * 16 + cs + k];
        }
        // epilogue: out for step T-1
#pragma unroll
        for (int k = 0; k < 8; k++)
            __builtin_nontemporal_store(hold[k],
                                        out_base + (size_t)(T_ - 1) * H_ + k);
    }
}

// ---------------------------------------------------------------------------
extern "C" void kernel_launch(void* const* d_in, const int* in_sizes, int n_in,
                              void* d_out, int out_size, void* d_ws, size_t ws_size,
                              hipStream_t stream) {
    const float* x   = (const float*)d_in[0];
    const float* Wih = (const float*)d_in[1];
    const float* Whh = (const float*)d_in[2];
    const float* bih = (const float*)d_in[3];
    const float* bhh = (const float*)d_in[4];
    float* out = (float*)d_out;
    unsigned* ws = (unsigned*)d_ws;

    // ring=8 needs 4KB flags + 8*64KB; fallback ring=2 fits 132KB.
    const size_t need8 = (size_t)(1024 + 8 * 16384) * sizeof(unsigned);
    const int ring = (ws_size >= need8) ? 8 : 2;

    k_init<<<64, 256, 0, stream>>>(ws, ring);
    k_xp<<<128 * 8, 256, 0, stream>>>(x, Wih, bih, bhh, out);
    k_rnn<<<NWAVE, 128, 0, stream>>>(Whh, out, ws, ring);
}